// Round 2
// 686.105 us; speedup vs baseline: 1.4559x; 1.4559x over previous
//
#include <hip/hip_runtime.h>

typedef __bf16 bf16x8 __attribute__((ext_vector_type(8)));
typedef __bf16 bf16x4 __attribute__((ext_vector_type(4)));
typedef float  f32x4  __attribute__((ext_vector_type(4)));

#define MFMA(A,B,C) __builtin_amdgcn_mfma_f32_16x16x32_bf16((A),(B),(C),0,0,0)

// ---------------- geometry ----------------
// vid: (4, 256, 256, 256) fp32. windows: 4*32*32 = 4096, each 64 tokens x 256 ch.
// NH=8, hd=32, scale = 32^-0.5.
//
// LDS plan (80928 B -> 2 blocks/CU, was 148512 -> 1 block/CU):
//   R1 [36864 B]: x (staging + af source)  ->  per-wave k/v scratch  ->  attn-out
//   QP [36864 B]: per-wave q  ->  per-wave P
//   TAB [7200 B]
// k and v B-fragments are held in registers (wave-private heads), transposed
// through the per-wave scratch slice of R1 after x is dead.

constexpr int XS_STRIDE = 264;   // x / attn-out rows (bf16); 528 B = 33*16 -> b128-aligned rows
constexpr int SC_STRIDE = 72;    // per-wave scratch stride; 144 B = 9*16 -> b128-aligned rows
constexpr int QP_STRIDE = 72;

constexpr int OFF_R1  = 0;       // 36864 = 4 waves * 64 * 72 * 2 (scratch is the max tenant)
constexpr int OFF_QP  = 36864;   // 4*64*72*2 = 36864
constexpr int OFF_TAB = 73728;   // 1800*4 = 7200
constexpr int LDS_BYTES = 80928; // 2 * 80928 = 161856 <= 163840 (160 KiB/CU)

// ---------------- weight re-pack: B-fragment order ----------------
// wfrag[ct][kt][lane][j], ct 0..47 = concat(q,k,v) col-tiles, ct 48..63 = proj.
// n = ct16*16 + (lane&15); k = kt*32 + (lane>>4)*8 + j.
__global__ void prep_weights(const float* __restrict__ wq,
                             const float* __restrict__ wkv,
                             const float* __restrict__ projw,
                             __bf16* __restrict__ wfrag)
{
    const int lane = threadIdx.x & 63;
    const int kt   = threadIdx.x >> 6;       // 0..7
    const int ct   = blockIdx.x;             // 0..63
    const int nl   = lane & 15;
    const int kk0  = kt * 32 + ((lane >> 4) << 3);
    __bf16* dst = wfrag + (((size_t)ct * 8 + kt) * 64 + lane) * 8;
    bf16x8 o;
#pragma unroll
    for (int j = 0; j < 8; ++j) {
        const int kk = kk0 + j;
        float v;
        if (ct < 16)       v = wq  [kk * 256 +             ct        * 16 + nl];
        else if (ct < 32)  v = wkv [kk * 512 +             (ct - 16) * 16 + nl];
        else if (ct < 48)  v = wkv [kk * 512 + 256 +       (ct - 32) * 16 + nl];
        else               v = projw[kk * 256 +            (ct - 48) * 16 + nl];
        o[j] = (__bf16)v;
    }
    *(bf16x8*)dst = o;
}

// ---------------- fused per-window kernel ----------------
__global__ __launch_bounds__(256, 2)   // force VGPR<=256 so 2 blocks/CU materialize
void attn_fused(const float* __restrict__ vid,
                const float* __restrict__ mod,
                const float* __restrict__ bq,
                const float* __restrict__ bkv,
                const float* __restrict__ projb,
                const float* __restrict__ table,
                const __bf16* __restrict__ wfrag,
                float* __restrict__ out)
{
    extern __shared__ char smem[];
    __bf16* s_xs  = (__bf16*)(smem + OFF_R1);   // x (stage/af), later attn-out (row=token, col=ch)
    __bf16* s_qp  = (__bf16*)(smem + OFF_QP);   // per-wave q, later P
    float*  s_tab = (float*)(smem + OFF_TAB);

    const int tid  = threadIdx.x;
    const int lane = tid & 63;
    const int wv   = tid >> 6;          // wave 0..3
    const int colL = lane & 15;
    const int quad = lane >> 4;
    const int kq   = quad << 3;         // frag k-offset (A/B operand)
    const int rowC = quad << 2;         // C/D row base

    // per-wave k/v transpose scratch inside R1 (alive only between af-load barrier
    // and the post-QKV barrier; x is dead, attn-out not yet written)
    __bf16* s_scr = (__bf16*)(smem + OFF_R1) + wv * (64 * SC_STRIDE);

    const int b  = blockIdx.x;
    const int tt = b >> 10;
    const int wy = (b >> 5) & 31;
    const int wx = b & 31;
    const int base0 = tt * (1 << 24) + wy * 8 * 65536 + wx * 8 * 256;

    // ---- stage x + modulator (fp32 add, bf16 store) and rel-pos table ----
#pragma unroll
    for (int i = 0; i < 16; ++i) {
        const int idx = tid + 256 * i;        // 0..4095
        const int m  = idx >> 6;
        const int c4 = (idx & 63) << 2;
        const int py = m >> 3, px = m & 7;
        const float4 xv = *(const float4*)(vid + base0 + py * 65536 + px * 256 + c4);
        const float4 mv = *(const float4*)(mod + m * 256 + c4);
        bf16x4 o;
        o[0] = (__bf16)(xv.x + mv.x);
        o[1] = (__bf16)(xv.y + mv.y);
        o[2] = (__bf16)(xv.z + mv.z);
        o[3] = (__bf16)(xv.w + mv.w);
        *(bf16x4*)&s_xs[m * XS_STRIDE + c4] = o;
    }
    for (int i = tid; i < 1800; i += 256) s_tab[i] = table[i];
    __syncthreads();

    // ---- load full A-operand (x) into registers, then x is dead ----
    bf16x8 af[4][8];
#pragma unroll
    for (int mt = 0; mt < 4; ++mt)
#pragma unroll
        for (int kt = 0; kt < 8; ++kt)
            af[mt][kt] = *(const bf16x8*)&s_xs[(mt * 16 + colL) * XS_STRIDE + kt * 32 + kq];
    __syncthreads();   // all waves done reading x before scratch overwrites R1

    const float SCALE = 0.17677669529663687f;   // 32^-0.5

    auto gemm8 = [&](int ct, float bias, f32x4 (&acc)[4]) {
#pragma unroll
        for (int mt = 0; mt < 4; ++mt) acc[mt] = {bias, bias, bias, bias};
        const bf16x8* wp = (const bf16x8*)wfrag + (size_t)(ct * 8) * 64 + lane;
#pragma unroll
        for (int kt = 0; kt < 8; ++kt) {
            const bf16x8 bf = wp[kt * 64];
#pragma unroll
            for (int mt = 0; mt < 4; ++mt) acc[mt] = MFMA(af[mt][kt], bf, acc[mt]);
        }
    };

    // ---- q: [64x256] @ [256x256], scaled, -> LDS (consumed as A-frags later) ----
#pragma unroll
    for (int ntl = 0; ntl < 4; ++ntl) {
        const int nloc = (wv * 4 + ntl) * 16 + colL;
        f32x4 acc[4];
        gemm8(wv * 4 + ntl, bq[nloc], acc);
#pragma unroll
        for (int mt = 0; mt < 4; ++mt)
#pragma unroll
            for (int r = 0; r < 4; ++r)
                s_qp[(wv * 64 + mt * 16 + rowC + r) * QP_STRIDE + ntl * 16 + colL] =
                    (__bf16)(acc[mt][r] * SCALE);
    }

    // ---- k: through per-wave scratch [tok][ch], then into B-frag registers ----
#pragma unroll
    for (int ntl = 0; ntl < 4; ++ntl) {
        const int nloc = (wv * 4 + ntl) * 16 + colL;
        f32x4 acc[4];
        gemm8(16 + wv * 4 + ntl, bkv[nloc], acc);
#pragma unroll
        for (int mt = 0; mt < 4; ++mt)
#pragma unroll
            for (int r = 0; r < 4; ++r)
                s_scr[(mt * 16 + rowC + r) * SC_STRIDE + ntl * 16 + colL] = (__bf16)acc[mt][r];
    }
    asm volatile("s_waitcnt lgkmcnt(0)" ::: "memory");   // k stores visible (wave-local)
    __builtin_amdgcn_sched_barrier(0);
    bf16x8 bk0[4], bk1[4];   // K B-frags for heads 2wv, 2wv+1 (local ch 0..31 / 32..63)
#pragma unroll
    for (int nt = 0; nt < 4; ++nt) {
        bk0[nt] = *(const bf16x8*)&s_scr[(nt * 16 + colL) * SC_STRIDE + kq];
        bk1[nt] = *(const bf16x8*)&s_scr[(nt * 16 + colL) * SC_STRIDE + 32 + kq];
    }
    asm volatile("s_waitcnt lgkmcnt(0)" ::: "memory");   // k reads retired before v overwrites
    __builtin_amdgcn_sched_barrier(0);

    // ---- v: through same scratch as v^T [ch][tok] (packed b64 stores), -> B-frags ----
#pragma unroll
    for (int ntl = 0; ntl < 4; ++ntl) {
        const int nloc = (wv * 4 + ntl) * 16 + colL;
        f32x4 acc[4];
        gemm8(32 + wv * 4 + ntl, bkv[256 + nloc], acc);
#pragma unroll
        for (int mt = 0; mt < 4; ++mt) {
            bf16x4 o;
            o[0] = (__bf16)acc[mt][0]; o[1] = (__bf16)acc[mt][1];
            o[2] = (__bf16)acc[mt][2]; o[3] = (__bf16)acc[mt][3];
            *(bf16x4*)&s_scr[(ntl * 16 + colL) * SC_STRIDE + mt * 16 + rowC] = o;
        }
    }
    asm volatile("s_waitcnt lgkmcnt(0)" ::: "memory");   // v stores visible (wave-local)
    __builtin_amdgcn_sched_barrier(0);
    bf16x8 bv0[2][2], bv1[2][2];   // V^T B-frags for the wave's two heads
#pragma unroll
    for (int n2 = 0; n2 < 2; ++n2)
#pragma unroll
        for (int k2 = 0; k2 < 2; ++k2) {
            bv0[n2][k2] = *(const bf16x8*)&s_scr[(n2 * 16 + colL) * SC_STRIDE + k2 * 32 + kq];
            bv1[n2][k2] = *(const bf16x8*)&s_scr[(32 + n2 * 16 + colL) * SC_STRIDE + k2 * 32 + kq];
        }
    __syncthreads();   // all scratch reads done; R1 becomes attn-out

    // ---- attention: wave wv handles heads 2wv, 2wv+1 (fully wave-private) ----
    int qcode[4][4];
#pragma unroll
    for (int mt = 0; mt < 4; ++mt)
#pragma unroll
        for (int r = 0; r < 4; ++r) {
            const int m = mt * 16 + rowC + r;
            qcode[mt][r] = (m >> 3) * 15 + (m & 7) + 112;
        }
    int kcode[4];
#pragma unroll
    for (int nt = 0; nt < 4; ++nt) {
        const int kn = nt * 16 + colL;
        kcode[nt] = (kn >> 3) * 15 + (kn & 7);
    }

    auto computeS = [&](int h, int hh, const bf16x8 (&bk)[4], float (&S)[4][4][4]) {
        bf16x8 aq[4];
#pragma unroll
        for (int mt = 0; mt < 4; ++mt)
            aq[mt] = *(const bf16x8*)&s_qp[(wv * 64 + mt * 16 + colL) * QP_STRIDE + hh * 32 + kq];
#pragma unroll
        for (int mt = 0; mt < 4; ++mt)
#pragma unroll
            for (int nt = 0; nt < 4; ++nt) {
                f32x4 c;
#pragma unroll
                for (int r = 0; r < 4; ++r)
                    c[r] = s_tab[(qcode[mt][r] - kcode[nt]) * 8 + h];
                c = MFMA(aq[mt], bk[nt], c);
#pragma unroll
                for (int r = 0; r < 4; ++r) S[mt][nt][r] = c[r];
            }
    };

    auto softmaxP = [&](float (&S)[4][4][4]) {
#pragma unroll
        for (int mt = 0; mt < 4; ++mt)
#pragma unroll
            for (int r = 0; r < 4; ++r) {
                float mx = S[mt][0][r];
#pragma unroll
                for (int nt = 1; nt < 4; ++nt) mx = fmaxf(mx, S[mt][nt][r]);
                mx = fmaxf(mx, __shfl_xor(mx, 1));
                mx = fmaxf(mx, __shfl_xor(mx, 2));
                mx = fmaxf(mx, __shfl_xor(mx, 4));
                mx = fmaxf(mx, __shfl_xor(mx, 8));
                float sum = 0.f;
#pragma unroll
                for (int nt = 0; nt < 4; ++nt) {
                    const float e = __expf(S[mt][nt][r] - mx);
                    S[mt][nt][r] = e;
                    sum += e;
                }
                sum += __shfl_xor(sum, 1);
                sum += __shfl_xor(sum, 2);
                sum += __shfl_xor(sum, 4);
                sum += __shfl_xor(sum, 8);
                const float inv = 1.0f / sum;
#pragma unroll
                for (int nt = 0; nt < 4; ++nt) S[mt][nt][r] *= inv;
            }
    };

    auto writeP = [&](const float (&S)[4][4][4]) {
#pragma unroll
        for (int mt = 0; mt < 4; ++mt)
#pragma unroll
            for (int nt = 0; nt < 4; ++nt)
#pragma unroll
                for (int r = 0; r < 4; ++r)
                    s_qp[(wv * 64 + mt * 16 + rowC + r) * QP_STRIDE + nt * 16 + colL] =
                        (__bf16)S[mt][nt][r];
    };

    auto pv = [&](int h, const bf16x8 (&bv)[2][2]) {
        bf16x8 ap[4][2];
#pragma unroll
        for (int mt = 0; mt < 4; ++mt)
#pragma unroll
            for (int k2 = 0; k2 < 2; ++k2)
                ap[mt][k2] = *(const bf16x8*)&s_qp[(wv * 64 + mt * 16 + colL) * QP_STRIDE + k2 * 32 + kq];
#pragma unroll
        for (int mt = 0; mt < 4; ++mt)
#pragma unroll
            for (int n2 = 0; n2 < 2; ++n2) {
                f32x4 o = {0.f, 0.f, 0.f, 0.f};
                o = MFMA(ap[mt][0], bv[n2][0], o);
                o = MFMA(ap[mt][1], bv[n2][1], o);
#pragma unroll
                for (int r = 0; r < 4; ++r)
                    s_xs[(mt * 16 + rowC + r) * XS_STRIDE + h * 32 + n2 * 16 + colL] = (__bf16)o[r];
            }
    };

    const int h0 = 2 * wv, h1 = 2 * wv + 1;
    float s0[4][4][4], s1[4][4][4];
    computeS(h0, 0, bk0, s0);
    softmaxP(s0);
    computeS(h1, 1, bk1, s1);      // q fully consumed after this
    writeP(s0);
    pv(h0, bv0);
    softmaxP(s1);
    writeP(s1);
    pv(h1, bv1);
    __syncthreads();

    // ---- proj: [64x256] @ [256x256] + scatter back to vid layout ----
    bf16x8 aA[4][8];
#pragma unroll
    for (int mt = 0; mt < 4; ++mt)
#pragma unroll
        for (int kt = 0; kt < 8; ++kt)
            aA[mt][kt] = *(const bf16x8*)&s_xs[(mt * 16 + colL) * XS_STRIDE + kt * 32 + kq];
#pragma unroll
    for (int ntl = 0; ntl < 4; ++ntl) {
        const int n = (wv * 4 + ntl) * 16 + colL;
        const float bias = projb[n];
        f32x4 acc[4];
#pragma unroll
        for (int mt = 0; mt < 4; ++mt) acc[mt] = {bias, bias, bias, bias};
        const bf16x8* wp = (const bf16x8*)wfrag + (size_t)((48 + wv * 4 + ntl) * 8) * 64 + lane;
#pragma unroll
        for (int kt = 0; kt < 8; ++kt) {
            const bf16x8 bf = wp[kt * 64];
#pragma unroll
            for (int mt = 0; mt < 4; ++mt) acc[mt] = MFMA(aA[mt][kt], bf, acc[mt]);
        }
#pragma unroll
        for (int mt = 0; mt < 4; ++mt)
#pragma unroll
            for (int r = 0; r < 4; ++r) {
                const int m = mt * 16 + rowC + r;
                out[base0 + (m >> 3) * 65536 + (m & 7) * 256 + n] = acc[mt][r];
            }
    }
}

extern "C" void kernel_launch(void* const* d_in, const int* in_sizes, int n_in,
                              void* d_out, int out_size, void* d_ws, size_t ws_size,
                              hipStream_t stream)
{
    const float* vid  = (const float*)d_in[0];
    const float* mod  = (const float*)d_in[1];
    const float* wq   = (const float*)d_in[2];
    const float* bq   = (const float*)d_in[3];
    const float* wkv  = (const float*)d_in[4];
    const float* bkv  = (const float*)d_in[5];
    const float* pw   = (const float*)d_in[6];
    const float* pb   = (const float*)d_in[7];
    const float* tab  = (const float*)d_in[8];
    __bf16* wfrag = (__bf16*)d_ws;   // 64*8*64*8 bf16 = 512 KB

    prep_weights<<<64, 512, 0, stream>>>(wq, wkv, pw, wfrag);

    // allow >64KB dynamic LDS (160 KiB/CU on gfx950); host-side, capture-safe
    (void)hipFuncSetAttribute((const void*)attn_fused,
                              hipFuncAttributeMaxDynamicSharedMemorySize, LDS_BYTES);
    attn_fused<<<4096, 256, LDS_BYTES, stream>>>(vid, mod, bq, bkv, pb, tab, wfrag,
                                                 (float*)d_out);
}